// Round 3
// baseline (299.424 us; speedup 1.0000x reference)
//
#include <hip/hip_runtime.h>
#include <hip/hip_bf16.h>

#define NBINS 128
#define NB2   (NBINS * NBINS)
#define TPB   256
#define NBLK  512
#define RAD   4
#define TAPS  (2 * RAD + 1)
#define MAXPART 64

// Kernel 1: per-block 64KB LDS fp32 histogram of truncated (+-4 sigma, 9x9)
// Gaussian KDE taps, then device-atomic merge into npart fp32 partials in ws.
// Inputs are float32 (evidence R1: bf16 reinterpretation of x produced NaN).
__global__ __launch_bounds__(TPB, 2) void kde_hist_kernel(
    const float* __restrict__ x,
    const float* __restrict__ ex,
    const float* __restrict__ ey,
    float* __restrict__ ws_total,
    float* __restrict__ partials,
    int n, int npart)
{
    __shared__ float h[NB2];
    __shared__ float red[TPB / 64];

    float4* h4 = (float4*)h;
    for (int i = threadIdx.x; i < NB2 / 4; i += TPB)
        h4[i] = make_float4(0.f, 0.f, 0.f, 0.f);

    const float lox = ex[0];
    const float bwx = ex[1] - ex[0];
    const float loy = ey[0];
    const float bwy = ey[1] - ey[0];
    const float ibx = 1.0f / bwx, iby = 1.0f / bwy;

    __syncthreads();

    float tsum = 0.f;
    const int stride = (int)gridDim.x * TPB;
    for (int p = (int)blockIdx.x * TPB + (int)threadIdx.x; p < n; p += stride) {
        // row p: cols 0,1 adjacent; 24B row stride -> naturally aligned 8B load
        const float2 xy = *(const float2*)(x + (size_t)p * 6);
        // t_i = (x - c_i)/bw = u - i with u = (x-lo)/bw - 0.5 (sigma units,
        // since bandwidth == bin width)
        const float u = (xy.x - lox) * ibx - 0.5f;
        const float v = (xy.y - loy) * iby - 0.5f;
        int ic = (int)floorf(u) - RAD;
        int jc = (int)floorf(v) - RAD;
        // clamp 9-tap window into grid; weights use the TRUE center, so a
        // clamped window just evaluates valid (tiny) far-tail weights at the
        // nearest in-grid bins -- exactly the bins the reference includes.
        ic = min(max(ic, 0), NBINS - TAPS);
        jc = min(max(jc, 0), NBINS - TAPS);

        float wx[TAPS], wy[TAPS];
        float sx = 0.f, sy = 0.f;
        #pragma unroll
        for (int k = 0; k < TAPS; ++k) {
            const float t = u - (float)(ic + k);
            const float w = __expf(-0.5f * t * t);
            wx[k] = w; sx += w;
            const float s = v - (float)(jc + k);
            const float w2 = __expf(-0.5f * s * s);
            wy[k] = w2; sy += w2;
        }
        tsum += sx * sy;  // exact sum of everything this point adds to h

        float* hb = h + ic * NBINS + jc;
        #pragma unroll
        for (int a = 0; a < TAPS; ++a) {
            #pragma unroll
            for (int b = 0; b < TAPS; ++b) {
                unsafeAtomicAdd(hb + a * NBINS + b, wx[a] * wy[b]);  // ds_add_f32
            }
        }
    }

    // block-reduce tsum -> one device atomic per block
    #pragma unroll
    for (int off = 32; off > 0; off >>= 1) tsum += __shfl_down(tsum, off, 64);
    if ((threadIdx.x & 63) == 0) red[threadIdx.x >> 6] = tsum;
    __syncthreads();

    // merge LDS hist into pre-zeroed partial copy (device-scope fp32 atomics)
    float* dst = partials + (size_t)((int)blockIdx.x % npart) * NB2;
    for (int i = threadIdx.x; i < NB2; i += TPB) unsafeAtomicAdd(dst + i, h[i]);

    if (threadIdx.x == 0) {
        float s = 0.f;
        #pragma unroll
        for (int w = 0; w < TPB / 64; ++w) s += red[w];
        unsafeAtomicAdd(ws_total, s);
    }
}

// Kernel 2: reduce partials, normalize to density, emit fp32.
__global__ __launch_bounds__(TPB) void kde_final_kernel(
    const float* __restrict__ partials,
    const float* __restrict__ ws_total,
    const float* __restrict__ ex,
    const float* __restrict__ ey,
    float* __restrict__ out,
    int npart)
{
    const int q = (int)blockIdx.x * TPB + (int)threadIdx.x;  // float4 group id
    float4 acc = make_float4(0.f, 0.f, 0.f, 0.f);
    for (int p = 0; p < npart; ++p) {
        const float4 v = ((const float4*)(partials + (size_t)p * NB2))[q];
        acc.x += v.x; acc.y += v.y; acc.z += v.z; acc.w += v.w;
    }
    const float bwx = ex[1] - ex[0];
    const float bwy = ey[1] - ey[0];
    const float inv = 1.0f / (ws_total[0] * bwx * bwy);
    float4 o4 = make_float4(acc.x * inv, acc.y * inv, acc.z * inv, acc.w * inv);
    ((float4*)out)[q] = o4;
}

extern "C" void kernel_launch(void* const* d_in, const int* in_sizes, int n_in,
                              void* d_out, int out_size, void* d_ws, size_t ws_size,
                              hipStream_t stream)
{
    const float* x  = (const float*)d_in[0];
    const float* ex = (const float*)d_in[1];
    const float* ey = (const float*)d_in[2];
    float* out = (float*)d_out;
    const int n = in_sizes[0] / 6;

    float* ws_total = (float*)d_ws;                   // ws[0]: grand total
    float* partials = (float*)((char*)d_ws + 64);     // 64B-aligned partials

    // npart fp32 partial copies (64KB each), capped at ~4.2MB of ws
    size_t fit = (ws_size > 64) ? (ws_size - 64) / (sizeof(float) * NB2) : 0;
    int npart = (int)((fit < (size_t)MAXPART) ? fit : (size_t)MAXPART);
    if (npart < 1) npart = 1;  // requires ws_size >= ~66KB

    const size_t zero_bytes = 64 + (size_t)npart * NB2 * sizeof(float);
    hipMemsetAsync(d_ws, 0, zero_bytes, stream);

    kde_hist_kernel<<<NBLK, TPB, 0, stream>>>(x, ex, ey, ws_total, partials, n, npart);
    kde_final_kernel<<<NB2 / 4 / TPB, TPB, 0, stream>>>(partials, ws_total, ex, ey, out, npart);
}